// Round 3
// baseline (705.638 us; speedup 1.0000x reference)
//
#include <hip/hip_runtime.h>

typedef unsigned short u16;
typedef __attribute__((ext_vector_type(8))) short short8;
typedef __attribute__((ext_vector_type(4))) float f32x4;

#define MFMA16(a, b, c) __builtin_amdgcn_mfma_f32_16x16x32_bf16((a), (b), (c), 0, 0, 0)

constexpr int Bb = 2, Ss = 4096, Tt = 4096, Dd = 512;
constexpr int BM = 64, BN = 64, TP = 4;
constexpr int TPART = Tt / TP;   // 1024
constexpr int TCH = TPART / BN;  // 16 T-chunks per partition

// ---- workspace layout (bytes) ----
constexpr size_t SZ_BF = (size_t)Bb * Ss * Dd * 2;  // 8,388,608 B: one bf16 [2][4096][512]
constexpr size_t O_QH  = 0;
constexpr size_t O_QL  = O_QH + SZ_BF;
constexpr size_t O_D2TH = O_QL + SZ_BF;
constexpr size_t O_D2TL = O_D2TH + SZ_BF;
constexpr size_t O_D3T  = O_D2TL + SZ_BF;
constexpr size_t O_D4T  = O_D3T + SZ_BF;
constexpr size_t O_CTX  = O_D4T + (size_t)512 * 512 * 2;
constexpr size_t O_OP   = O_CTX + SZ_BF;
constexpr size_t O_MP   = O_OP + (size_t)TP * SZ_BF;
constexpr size_t O_LP   = O_MP + (size_t)TP * Bb * Ss * 4;

__device__ __forceinline__ u16 f2bf(float x) {
  union { float f; unsigned u; } v; v.f = x;
  unsigned r = v.u + 0x7fffu + ((v.u >> 16) & 1u);  // RNE
  return (u16)(r >> 16);
}
__device__ __forceinline__ float bf2f(u16 h) {
  union { unsigned u; float f; } v; v.u = ((unsigned)h) << 16;
  return v.f;
}

// async global->LDS DMA, 16B per lane. LDS dest: wave-uniform base + lane*16.
__device__ __forceinline__ void gl_lds16(const u16* g, u16* l) {
  __builtin_amdgcn_global_load_lds((const __attribute__((address_space(1))) void*)g,
                                   (__attribute__((address_space(3))) void*)l, 16, 0, 0);
}

// pinned 16B global->reg load (inline asm so the vmcnt queue order is exactly
// as scheduled; a plain load could be sunk by the compiler, invalidating the
// hand-counted s_waitcnt ledger). Completion is guaranteed by the manual
// vmcnt(N) waits, NOT by compiler-tracked dependencies.
__device__ __forceinline__ void gload_b128(short8& dst, const u16* p) {
  asm volatile("global_load_dwordx4 %0, %1, off" : "=v"(dst) : "v"(p) : "memory");
}

// elementwise f32 -> bf16 hi + bf16 lo-residual (no transpose; d1 is already [b][s][d])
__global__ void cvt_split_kernel(const float* __restrict__ in,
                                 u16* __restrict__ outh, u16* __restrict__ outl) {
  const int i = blockIdx.x * 256 + threadIdx.x;
  float4 v = ((const float4*)in)[i];
  ushort4 hh, ll;
  hh.x = f2bf(v.x); ll.x = f2bf(v.x - bf2f(hh.x));
  hh.y = f2bf(v.y); ll.y = f2bf(v.y - bf2f(hh.y));
  hh.z = f2bf(v.z); ll.z = f2bf(v.z - bf2f(hh.z));
  hh.w = f2bf(v.w); ll.w = f2bf(v.w - bf2f(hh.w));
  ((ushort4*)outh)[i] = hh;
  ((ushort4*)outl)[i] = ll;
}

// in: [batch][R][C] f32  ->  outh/outl: [batch][C][R] bf16 (hi, optional lo residual)
__global__ void transpose_split_kernel(const float* __restrict__ in,
                                       u16* __restrict__ outh,
                                       u16* __restrict__ outl,
                                       int R, int C) {
  __shared__ float tile[32][33];
  int b = blockIdx.z;
  const float* inb = in + (size_t)b * R * C;
  int x = blockIdx.x * 32 + threadIdx.x;
  int y0 = blockIdx.y * 32;
  for (int j = threadIdx.y; j < 32; j += 8)
    tile[j][threadIdx.x] = inb[(size_t)(y0 + j) * C + x];
  __syncthreads();
  size_t ob = (size_t)b * C * R;
  for (int j = threadIdx.y; j < 32; j += 8) {
    float v = tile[threadIdx.x][j];
    size_t oi = ob + (size_t)(blockIdx.x * 32 + j) * R + (y0 + threadIdx.x);
    u16 h = f2bf(v);
    outh[oi] = h;
    if (outl) outl[oi] = f2bf(v - bf2f(h));
  }
}

// Flash attention partial over one T-partition.
// grid (Ss/BM=64, TP, Bb), block 256 (4 waves; wave w owns Q-rows w*16..w*16+15)
// v4: counted-vmcnt deep pipeline (T3+T4), ring of 4 LDS buffers.
//  - 12 units/tc: u0..7 = K chunks (QK^T), u8..11 = V chunks (PV)
//  - DMA d(u+3) issued at top of unit u -> ~3 intervals in flight
//  - Q fragments: pinned asm loads, 3-slot register rotation, 2 units ahead
//  - per-unit: s_waitcnt vmcnt(VMW[u]) lgkmcnt(0); s_barrier; issue; compute
//  - vmcnt ledger (4 ops per K/V/Q batch), verified unit-by-unit:
//      queue at u0: d0,Q0,d1,Q1,d2 -> need d0,Q0 -> vmcnt(12); etc.
//  - launch_bounds(256,2): 256 regs/wave. o_acc 128 + s_acc 16 + Qslots 48 fits.
__global__ __launch_bounds__(256, 2)
void flash_part_kernel(const u16* __restrict__ qh_g,
                       const u16* __restrict__ ql_g,
                       const u16* __restrict__ d2th,
                       const u16* __restrict__ d2tl,
                       const u16* __restrict__ d3t,
                       u16* __restrict__ opart,
                       float* __restrict__ mpart,
                       float* __restrict__ lpart) {
  // ring unit: K -> [0..4095]=kh 64r x 64c, [4096..8191]=kl ; V -> 128r x 64c flat
  __shared__ __align__(1024) u16 sbuf[4][8192];
  __shared__ __align__(16) u16 ph[64 * 72];

  const int tid = threadIdx.x;
  const int wave = tid >> 6, lane = tid & 63, quad = lane >> 4, l15 = lane & 15;
  const int m0 = wave * 16;
  const int s0 = blockIdx.x * BM, tp = blockIdx.y, b = blockIdx.z;
  const int rr = lane >> 3, sl = lane & 7;  // DMA: row-in-group, slot
  const int x7 = l15 & 7;                   // read-side swizzle key (== row&7)

  f32x4 o_acc[32];
#pragma unroll
  for (int i = 0; i < 32; i++) o_acc[i] = (f32x4){0.f, 0.f, 0.f, 0.f};
  float m_r[4] = {-INFINITY, -INFINITY, -INFINITY, -INFINITY};
  float l_r[4] = {0.f, 0.f, 0.f, 0.f};

  const u16* qh_row = qh_g + ((size_t)b * Ss + s0 + m0 + l15) * Dd + quad * 8;
  const u16* ql_row = ql_g + ((size_t)b * Ss + s0 + m0 + l15) * Dd + quad * 8;
  const u16* kh_b = d2th + (size_t)b * Tt * Dd;
  const u16* kl_b = d2tl + (size_t)b * Tt * Dd;
  const u16* v_b  = d3t  + (size_t)b * Dd * Tt;

  // Q register slots: slot = unit%3; each = 2 k-slices (hi+lo) = 16 VGPRs
  short8 qh_s[3][2], ql_s[3][2];

  // K unit: 64 t-rows x 64 d-cols hi+lo (16 KB), 4 DMA ops/lane.
  auto issueK = [&](int t0_, int d0_, int bp) {
#pragma unroll
    for (int i = 0; i < 2; i++) {
      const int r0 = wave * 16 + i * 8;
      const int r = r0 + rr;
      const size_t so = (size_t)(t0_ + r) * Dd + d0_ + ((sl ^ rr) << 3);
      gl_lds16(kh_b + so, &sbuf[bp][r0 * 64]);
      gl_lds16(kl_b + so, &sbuf[bp][4096 + r0 * 64]);
    }
  };
  // V unit: 128 d-rows x 64 t-cols (16 KB), 4 DMA ops/lane.
  auto issueV = [&](int t0_, int nc, int bp) {
#pragma unroll
    for (int i = 0; i < 4; i++) {
      const int r0 = wave * 32 + i * 8;
      const int r = r0 + rr;
      gl_lds16(v_b + (size_t)(nc * 128 + r) * Tt + t0_ + ((sl ^ rr) << 3),
               &sbuf[bp][r0 * 64]);
    }
  };
  // Q unit uq (d-cols uq*64..+63): 4 pinned loads into slot.
  auto issueQ = [&](int uq, int slot) {
    gload_b128(qh_s[slot][0], qh_row + (2 * uq) * 32);
    gload_b128(qh_s[slot][1], qh_row + (2 * uq + 1) * 32);
    gload_b128(ql_s[slot][0], ql_row + (2 * uq) * 32);
    gload_b128(ql_s[slot][1], ql_row + (2 * uq + 1) * 32);
  };

  // allowed-outstanding (in units of VMEM ops) at each unit's wait
  constexpr int VMW[12] = {12, 12, 12, 12, 12, 12, 12, 8, 8, 8, 8, 12};

  // prologue: build the steady-state queue  d0,Q0,d1,Q1,d2
  const int t00 = tp * TPART;
  issueK(t00, 0, 0);
  issueQ(0, 0);
  issueK(t00, 64, 1);
  issueQ(1, 1);
  issueK(t00, 128, 2);

  for (int tc = 0; tc < TCH; tc++) {
    const int t0 = t00 + tc * BN;
    const int tcn = (tc + 1 < TCH) ? tc + 1 : 0;  // wrap: dead prefetch, drained at end
    const int t0n = t00 + tcn * BN;
    f32x4 s_acc[4];
#pragma unroll
    for (int nt = 0; nt < 4; nt++) s_acc[nt] = (f32x4){0.f, 0.f, 0.f, 0.f};

#pragma unroll
    for (int u = 0; u < 12; u++) {
      // ---- online softmax between QK^T (u7) and PV (u8); own-wave data only ----
      if (u == 8) {
        float alpha[4], psum[4];
#pragma unroll
        for (int r = 0; r < 4; r++) {
          float v = fmaxf(fmaxf(s_acc[0][r], s_acc[1][r]), fmaxf(s_acc[2][r], s_acc[3][r]));
          v = fmaxf(v, __shfl_xor(v, 1));
          v = fmaxf(v, __shfl_xor(v, 2));
          v = fmaxf(v, __shfl_xor(v, 4));
          v = fmaxf(v, __shfl_xor(v, 8));
          float mn = fmaxf(m_r[r], v);
          alpha[r] = __expf(m_r[r] - mn);
          m_r[r] = mn;
          psum[r] = 0.f;
        }
#pragma unroll
        for (int nt = 0; nt < 4; nt++) {
#pragma unroll
          for (int r = 0; r < 4; r++) {
            float p = __expf(s_acc[nt][r] - m_r[r]);
            psum[r] += p;
            ph[(m0 + quad * 4 + r) * 72 + nt * 16 + l15] = f2bf(p);
          }
        }
#pragma unroll
        for (int r = 0; r < 4; r++) {
          float v = psum[r];
          v += __shfl_xor(v, 1);
          v += __shfl_xor(v, 2);
          v += __shfl_xor(v, 4);
          v += __shfl_xor(v, 8);
          l_r[r] = l_r[r] * alpha[r] + v;
        }
#pragma unroll
        for (int j = 0; j < 32; j++) {
#pragma unroll
          for (int r = 0; r < 4; r++) o_acc[j][r] *= alpha[r];
        }
      }

      // ---- wait (own DMA/Q for unit u done) + barrier (everyone's done) ----
      asm volatile("s_waitcnt vmcnt(%0) lgkmcnt(0)" :: "i"(VMW[u]) : "memory");
      __builtin_amdgcn_s_barrier();
      __builtin_amdgcn_sched_barrier(0);

      // ---- issue stage (order must match the vmcnt ledger: Q before d) ----
      if (u <= 5) {
        issueQ(u + 2, (u + 2) % 3);
        if (u < 5) issueK(t0, (u + 3) * 64, (u + 3) & 3);  // d3..d7
        else       issueV(t0, 0, 0);                        // d8 = V0 -> buf0
      } else if (u == 6)  issueV(t0, 1, 1);                 // d9
      else if (u == 7)    issueV(t0, 2, 2);                 // d10
      else if (u == 8)    issueV(t0, 3, 3);                 // d11
      else if (u == 9)    issueK(t0n, 0, 0);                // d0' (next tc)
      else if (u == 10) { issueQ(0, 0); issueK(t0n, 64, 1); }   // Q0', d1'
      else              { issueQ(1, 1); issueK(t0n, 128, 2); }  // Q1', d2'
      __builtin_amdgcn_sched_barrier(0);

      // ---- compute unit u from buf[u&3] ----
      if (u < 8) {
        __builtin_amdgcn_s_setprio(1);
#pragma unroll
        for (int ks = 0; ks < 2; ks++) {
          const int go = ((ks * 4 + quad) ^ x7) << 3;
#pragma unroll
          for (int nt = 0; nt < 4; nt++) {
            const int off = (nt * 16 + l15) * 64 + go;
            short8 bh = *(const short8*)&sbuf[u & 3][off];
            short8 bl = *(const short8*)&sbuf[u & 3][4096 + off];
            s_acc[nt] = MFMA16(qh_s[u % 3][ks], bh, s_acc[nt]);
            s_acc[nt] = MFMA16(ql_s[u % 3][ks], bh, s_acc[nt]);
            s_acc[nt] = MFMA16(qh_s[u % 3][ks], bl, s_acc[nt]);
          }
        }
        __builtin_amdgcn_s_setprio(0);
      } else {
        const int nc = u - 8;
        __builtin_amdgcn_s_setprio(1);
#pragma unroll
        for (int ks = 0; ks < 2; ks++) {
          const int kk = ks * 32 + quad * 8;
          const int go = ((ks * 4 + quad) ^ x7) << 3;
          short8 ap = *(const short8*)&ph[(m0 + l15) * 72 + kk];
#pragma unroll
          for (int nt = 0; nt < 8; nt++) {
            const int off = (nt * 16 + l15) * 64 + go;
            short8 bv = *(const short8*)&sbuf[u & 3][off];
            o_acc[nc * 8 + nt] = MFMA16(ap, bv, o_acc[nc * 8 + nt]);
          }
        }
        __builtin_amdgcn_s_setprio(0);
      }
    }
  }

  // drain wrap-around prefetches before epilogue (in-flight DMA at endpgm could
  // land in a successor block's LDS allocation)
  asm volatile("s_waitcnt vmcnt(0)" ::: "memory");

  // ---- epilogue: unnormalized partial O (bf16) + m/l stats ----
  const size_t obase = (((size_t)tp * Bb + b) * Ss + s0) * Dd;
#pragma unroll
  for (int j = 0; j < 32; j++) {
    const int col = (j >> 3) * 128 + (j & 7) * 16 + l15;
#pragma unroll
    for (int r = 0; r < 4; r++) {
      const int row = m0 + quad * 4 + r;
      opart[obase + (size_t)row * Dd + col] = f2bf(o_acc[j][r]);
    }
  }
  if (l15 == 0) {
    const size_t sbase = ((size_t)tp * Bb + b) * Ss + s0;
#pragma unroll
    for (int r = 0; r < 4; r++) {
      const int row = m0 + quad * 4 + r;
      mpart[sbase + row] = m_r[r];
      lpart[sbase + row] = l_r[r];
    }
  }
}

// Merge TP partitions: ctx = sum_p e^{m_p-M} O_p / sum_p e^{m_p-M} l_p
__global__ void combine_kernel(const u16* __restrict__ opart,
                               const float* __restrict__ mpart,
                               const float* __restrict__ lpart,
                               u16* __restrict__ ctx) {
  const int idx = blockIdx.x * blockDim.x + threadIdx.x;  // vec8 index
  const int vpr = Dd / 8;
  const int row = idx / vpr;         // b*Ss + s
  const int dv = (idx % vpr) * 8;
  float mv[TP], mM = -INFINITY;
#pragma unroll
  for (int p = 0; p < TP; p++) {
    mv[p] = mpart[(size_t)p * Bb * Ss + row];
    mM = fmaxf(mM, mv[p]);
  }
  float w[TP], denom = 0.f;
#pragma unroll
  for (int p = 0; p < TP; p++) {
    float e = __expf(mv[p] - mM);
    w[p] = e;
    denom += e * lpart[(size_t)p * Bb * Ss + row];
  }
  const float inv = 1.0f / denom;
  float acc[8];
#pragma unroll
  for (int e = 0; e < 8; e++) acc[e] = 0.f;
#pragma unroll
  for (int p = 0; p < TP; p++) {
    uint4 raw = *(const uint4*)&opart[(size_t)p * Bb * Ss * Dd + (size_t)row * Dd + dv];
    const u16* u = (const u16*)&raw;
#pragma unroll
    for (int e = 0; e < 8; e++) acc[e] += w[p] * bf2f(u[e]);
  }
  u16 outv[8];
#pragma unroll
  for (int e = 0; e < 8; e++) outv[e] = f2bf(acc[e] * inv);
  *(uint4*)&ctx[(size_t)row * Dd + dv] = *(const uint4*)outv;
}

// out[8192,512] = ctx_bf16 @ d4 + d5 ; 128x128 tile, 256 thr, wave = 64x64
__global__ __launch_bounds__(256, 2)
void proj_kernel(const u16* __restrict__ ctx,
                 const u16* __restrict__ d4t,  // [n][k]
                 const float* __restrict__ d5,
                 float* __restrict__ out) {
  __shared__ u16 a_lds[128 * 40], b_lds[128 * 40];
  const int tid = threadIdx.x;
  const int wave = tid >> 6, lane = tid & 63, quad = lane >> 4, l15 = lane & 15;
  const int m0w = (wave & 1) * 64, n0w = (wave >> 1) * 64;
  const int bm = blockIdx.x, bn = blockIdx.y;
  f32x4 acc[4][4];
#pragma unroll
  for (int i = 0; i < 4; i++)
#pragma unroll
    for (int j = 0; j < 4; j++) acc[i][j] = (f32x4){0.f, 0.f, 0.f, 0.f};

  const int srow = tid >> 2, scol = (tid & 3) * 8;
  for (int kt = 0; kt < 16; kt++) {
    const int k0 = kt * 32;
    __syncthreads();
#pragma unroll
    for (int pass = 0; pass < 2; pass++) {
      const int row = srow + pass * 64;
      *(uint4*)&a_lds[row * 40 + scol] =
          *(const uint4*)&ctx[(size_t)(bm * 128 + row) * Dd + k0 + scol];
      *(uint4*)&b_lds[row * 40 + scol] =
          *(const uint4*)&d4t[(size_t)(bn * 128 + row) * Dd + k0 + scol];
    }
    __syncthreads();
    short8 af[4], bfr[4];
#pragma unroll
    for (int i = 0; i < 4; i++)
      af[i] = *(const short8*)&a_lds[(m0w + 16 * i + l15) * 40 + quad * 8];
#pragma unroll
    for (int j = 0; j < 4; j++)
      bfr[j] = *(const short8*)&b_lds[(n0w + 16 * j + l15) * 40 + quad * 8];
#pragma unroll
    for (int i = 0; i < 4; i++)
#pragma unroll
      for (int j = 0; j < 4; j++) acc[i][j] = MFMA16(af[i], bfr[j], acc[i][j]);
  }
#pragma unroll
  for (int j = 0; j < 4; j++) {
    const int colg = bn * 128 + n0w + 16 * j + l15;
    const float bias = d5[colg];
#pragma unroll
    for (int i = 0; i < 4; i++) {
#pragma unroll
      for (int r = 0; r < 4; r++) {
        const int rowg = bm * 128 + m0w + 16 * i + quad * 4 + r;
        out[(size_t)rowg * 512 + colg] = acc[i][j][r] + bias;
      }
    }
  }
}

extern "C" void kernel_launch(void* const* d_in, const int* in_sizes, int n_in,
                              void* d_out, int out_size, void* d_ws, size_t ws_size,
                              hipStream_t stream) {
  (void)in_sizes; (void)n_in; (void)out_size; (void)ws_size;
  const float* d1 = (const float*)d_in[0];
  const float* d2 = (const float*)d_in[1];
  const float* d3 = (const float*)d_in[2];
  const float* d4 = (const float*)d_in[3];
  const float* d5 = (const float*)d_in[4];
  float* out = (float*)d_out;
  char* ws = (char*)d_ws;

  u16* qh_g = (u16*)(ws + O_QH);
  u16* ql_g = (u16*)(ws + O_QL);
  u16* d2th = (u16*)(ws + O_D2TH);
  u16* d2tl = (u16*)(ws + O_D2TL);
  u16* d3t  = (u16*)(ws + O_D3T);
  u16* d4t  = (u16*)(ws + O_D4T);
  u16* ctx  = (u16*)(ws + O_CTX);
  u16* opart = (u16*)(ws + O_OP);
  float* mpart = (float*)(ws + O_MP);
  float* lpart = (float*)(ws + O_LP);

  // d1 [b][s][d] -> bf16 hi/lo (elementwise)
  cvt_split_kernel<<<(Bb * Ss * Dd / 4) / 256, 256, 0, stream>>>(d1, qh_g, ql_g);
  // d2 [b][512][4096] -> [b][t][d] hi+lo
  transpose_split_kernel<<<dim3(128, 16, 2), dim3(32, 8), 0, stream>>>(d2, d2th, d2tl, 512, 4096);
  // d3 [b][4096][512] -> [b][d][t] hi only
  transpose_split_kernel<<<dim3(16, 128, 2), dim3(32, 8), 0, stream>>>(d3, d3t, nullptr, 4096, 512);
  // d4 [512][512] -> [n][k] hi only
  transpose_split_kernel<<<dim3(16, 16, 1), dim3(32, 8), 0, stream>>>(d4, d4t, nullptr, 512, 512);

  flash_part_kernel<<<dim3(Ss / BM, TP, Bb), 256, 0, stream>>>(qh_g, ql_g, d2th, d2tl, d3t,
                                                               opart, mpart, lpart);
  combine_kernel<<<(Bb * Ss * Dd / 8) / 256, 256, 0, stream>>>(opart, mpart, lpart, ctx);
  proj_kernel<<<dim3(64, 4), 256, 0, stream>>>(ctx, d4t, d5, out);
}

// Round 4
// 620.008 us; speedup vs baseline: 1.1381x; 1.1381x over previous
//
#include <hip/hip_runtime.h>

typedef unsigned short u16;
typedef __attribute__((ext_vector_type(8))) short short8;
typedef __attribute__((ext_vector_type(4))) float f32x4;

#define MFMA16(a, b, c) __builtin_amdgcn_mfma_f32_16x16x32_bf16((a), (b), (c), 0, 0, 0)

constexpr int Bb = 2, Ss = 4096, Tt = 4096, Dd = 512;
constexpr int BM = 64, BN = 64, TP = 4;
constexpr int TPART = Tt / TP;   // 1024
constexpr int TCH = TPART / BN;  // 16 T-chunks per partition

// ---- workspace layout (bytes) ----
constexpr size_t SZ_BF = (size_t)Bb * Ss * Dd * 2;  // 8,388,608 B: one bf16 [2][4096][512]
constexpr size_t O_QH  = 0;
constexpr size_t O_QL  = O_QH + SZ_BF;
constexpr size_t O_D2TH = O_QL + SZ_BF;
constexpr size_t O_D2TL = O_D2TH + SZ_BF;
constexpr size_t O_D3T  = O_D2TL + SZ_BF;
constexpr size_t O_D4T  = O_D3T + SZ_BF;
constexpr size_t O_CTX  = O_D4T + (size_t)512 * 512 * 2;
constexpr size_t O_OP   = O_CTX + SZ_BF;
constexpr size_t O_MP   = O_OP + (size_t)TP * SZ_BF;
constexpr size_t O_LP   = O_MP + (size_t)TP * Bb * Ss * 4;

__device__ __forceinline__ u16 f2bf(float x) {
  union { float f; unsigned u; } v; v.f = x;
  unsigned r = v.u + 0x7fffu + ((v.u >> 16) & 1u);  // RNE
  return (u16)(r >> 16);
}
__device__ __forceinline__ float bf2f(u16 h) {
  union { unsigned u; float f; } v; v.u = ((unsigned)h) << 16;
  return v.f;
}

// async global->LDS DMA, 16B per lane. LDS dest: wave-uniform base + lane*16.
__device__ __forceinline__ void gl_lds16(const u16* g, u16* l) {
  __builtin_amdgcn_global_load_lds((const __attribute__((address_space(1))) void*)g,
                                   (__attribute__((address_space(3))) void*)l, 16, 0, 0);
}

// elementwise f32 -> bf16 hi + bf16 lo-residual (no transpose; d1 is already [b][s][d])
__global__ void cvt_split_kernel(const float* __restrict__ in,
                                 u16* __restrict__ outh, u16* __restrict__ outl) {
  const int i = blockIdx.x * 256 + threadIdx.x;
  float4 v = ((const float4*)in)[i];
  ushort4 hh, ll;
  hh.x = f2bf(v.x); ll.x = f2bf(v.x - bf2f(hh.x));
  hh.y = f2bf(v.y); ll.y = f2bf(v.y - bf2f(hh.y));
  hh.z = f2bf(v.z); ll.z = f2bf(v.z - bf2f(hh.z));
  hh.w = f2bf(v.w); ll.w = f2bf(v.w - bf2f(hh.w));
  ((ushort4*)outh)[i] = hh;
  ((ushort4*)outl)[i] = ll;
}

// in: [batch][R][C] f32  ->  outh/outl: [batch][C][R] bf16 (hi, optional lo residual)
__global__ void transpose_split_kernel(const float* __restrict__ in,
                                       u16* __restrict__ outh,
                                       u16* __restrict__ outl,
                                       int R, int C) {
  __shared__ float tile[32][33];
  int b = blockIdx.z;
  const float* inb = in + (size_t)b * R * C;
  int x = blockIdx.x * 32 + threadIdx.x;
  int y0 = blockIdx.y * 32;
  for (int j = threadIdx.y; j < 32; j += 8)
    tile[j][threadIdx.x] = inb[(size_t)(y0 + j) * C + x];
  __syncthreads();
  size_t ob = (size_t)b * C * R;
  for (int j = threadIdx.y; j < 32; j += 8) {
    float v = tile[threadIdx.x][j];
    size_t oi = ob + (size_t)(blockIdx.x * 32 + j) * R + (y0 + threadIdx.x);
    u16 h = f2bf(v);
    outh[oi] = h;
    if (outl) outl[oi] = f2bf(v - bf2f(h));
  }
}

// Flash attention partial over one T-partition.
// v5: v3's spill-free schedule with doubled units + XCD-clustered dispatch.
//  - grid: 1D 512 blocks. wg&7 -> (tp,b) so all 64 s-blocks of one K/V
//    partition (3MB, fits 4MB L2) occupy exactly one XCD's 64 block slots.
//  - units/tc: 4x K (64t x 128d, hi+lo, 32KB) + 2x V (256d x 64t, 32KB);
//    2x32KB LDS double buffer, DMA for unit u+1 issued before compute(u),
//    one __syncthreads per unit (drains DMA).
//  - NO persistent staging registers (v2/v4 lesson: zero headroom beyond
//    o_acc128+s_acc16). Q fragments re-read per unit from global (L2-warm).
//  - both-sides XOR granule swizzle -> conflict-free unpadded LDS rows.
__global__ __launch_bounds__(256, 2)
void flash_part_kernel(const u16* __restrict__ qh_g,
                       const u16* __restrict__ ql_g,
                       const u16* __restrict__ d2th,
                       const u16* __restrict__ d2tl,
                       const u16* __restrict__ d3t,
                       u16* __restrict__ opart,
                       float* __restrict__ mpart,
                       float* __restrict__ lpart) {
  // buffer: K unit -> [0..8191]=kh 64r x 128c, [8192..16383]=kl
  //         V unit -> 256r x 64c flat (fills all 16384)
  __shared__ __align__(1024) u16 sbuf[2][16384];
  __shared__ __align__(16) u16 ph[64 * 72];

  const int tid = threadIdx.x;
  const int wave = tid >> 6, lane = tid & 63, quad = lane >> 4, l15 = lane & 15;
  const int m0 = wave * 16;
  // XCD-clustered decode: xcd = wg&7 (dispatch round-robins XCDs), one (tp,b) per XCD
  const int wg = blockIdx.x;
  const int xcd = wg & 7, sblk = wg >> 3;
  const int tp = xcd >> 1, b = xcd & 1;
  const int s0 = sblk * BM;
  const int x7 = l15 & 7;  // read-side swizzle key (== row&7)

  f32x4 o_acc[32];
#pragma unroll
  for (int i = 0; i < 32; i++) o_acc[i] = (f32x4){0.f, 0.f, 0.f, 0.f};
  float m_r[4] = {-INFINITY, -INFINITY, -INFINITY, -INFINITY};
  float l_r[4] = {0.f, 0.f, 0.f, 0.f};

  const u16* qh_row = qh_g + ((size_t)b * Ss + s0 + m0 + l15) * Dd + quad * 8;
  const u16* ql_row = ql_g + ((size_t)b * Ss + s0 + m0 + l15) * Dd + quad * 8;
  const u16* kh_b = d2th + (size_t)b * Tt * Dd;
  const u16* kl_b = d2tl + (size_t)b * Tt * Dd;
  const u16* v_b  = d3t  + (size_t)b * Dd * Tt;

  // K unit: 64 t-rows x 128 d-cols (16 slots of 16B/row), hi+lo. 8 DMA/lane.
  // wave w stages rows w*16..w*16+15, 4 rows per issue (64 lanes x 16B = 4x256B).
  const int kr4 = lane >> 4, ks16 = lane & 15;  // row-in-4group, slot
  auto issueK = [&](int t0_, int d0_, int bp) {
#pragma unroll
    for (int i = 0; i < 4; i++) {
      const int r0 = wave * 16 + i * 4;
      const int r = r0 + kr4;
      const size_t so = (size_t)(t0_ + r) * Dd + d0_ + ((ks16 ^ (r & 7)) << 3);
      gl_lds16(kh_b + so, &sbuf[bp][r0 * 128]);
      gl_lds16(kl_b + so, &sbuf[bp][8192 + r0 * 128]);
    }
  };
  // V unit: 256 d-rows x 64 t-cols (8 slots/row). 8 DMA/lane.
  // wave w stages rows w*64..w*64+63, 8 rows per issue.
  const int vr8 = lane >> 3, vs8 = lane & 7;
  auto issueV = [&](int t0_, int vh, int bp) {
#pragma unroll
    for (int i = 0; i < 8; i++) {
      const int r0 = wave * 64 + i * 8;
      const int r = r0 + vr8;
      gl_lds16(v_b + (size_t)(vh * 256 + r) * Tt + t0_ + ((vs8 ^ (r & 7)) << 3),
               &sbuf[bp][r0 * 64]);
    }
  };

  const int t00 = tp * TPART;
  // prologue: stage K unit 0 of tc 0 into buf0
  issueK(t00, 0, 0);
  __syncthreads();

  for (int tc = 0; tc < TCH; tc++) {
    const int t0 = t00 + tc * BN;
    f32x4 s_acc[4];
#pragma unroll
    for (int nt = 0; nt < 4; nt++) s_acc[nt] = (f32x4){0.f, 0.f, 0.f, 0.f};

    // ---- QK^T: 4 units of 128 d-cols, dbuf parity p = ds&1 ----
#pragma unroll
    for (int ds = 0; ds < 4; ds++) {
      const int p = ds & 1;
      if (ds < 3) issueK(t0, (ds + 1) * 128, p ^ 1);
      else        issueV(t0, 0, p ^ 1);
      // Q fragments straight from global (L2-resident; transient 64 VGPRs)
      const int d0 = ds * 128;
      short8 ah[4], al[4];
#pragma unroll
      for (int ks = 0; ks < 4; ks++) {
        ah[ks] = *(const short8*)(qh_row + d0 + ks * 32);
        al[ks] = *(const short8*)(ql_row + d0 + ks * 32);
      }
      __builtin_amdgcn_s_setprio(1);
#pragma unroll
      for (int ks = 0; ks < 4; ks++) {
        const int go = ((ks * 4 + quad) ^ x7) << 3;
#pragma unroll
        for (int nt = 0; nt < 4; nt++) {
          const int off = (nt * 16 + l15) * 128 + go;
          short8 bh = *(const short8*)&sbuf[p][off];
          short8 bl = *(const short8*)&sbuf[p][8192 + off];
          s_acc[nt] = MFMA16(ah[ks], bh, s_acc[nt]);
          s_acc[nt] = MFMA16(al[ks], bh, s_acc[nt]);
          s_acc[nt] = MFMA16(ah[ks], bl, s_acc[nt]);
        }
      }
      __builtin_amdgcn_s_setprio(0);
      __syncthreads();  // drains next unit's DMA; releases read buffer
    }

    // ---- online softmax (C layout: row=quad*4+r, col=nt*16+l15; rows intra-wave) ----
    float alpha[4], psum[4];
#pragma unroll
    for (int r = 0; r < 4; r++) {
      float v = fmaxf(fmaxf(s_acc[0][r], s_acc[1][r]), fmaxf(s_acc[2][r], s_acc[3][r]));
      v = fmaxf(v, __shfl_xor(v, 1));
      v = fmaxf(v, __shfl_xor(v, 2));
      v = fmaxf(v, __shfl_xor(v, 4));
      v = fmaxf(v, __shfl_xor(v, 8));
      float mn = fmaxf(m_r[r], v);
      alpha[r] = __expf(m_r[r] - mn);
      m_r[r] = mn;
      psum[r] = 0.f;
    }
#pragma unroll
    for (int nt = 0; nt < 4; nt++) {
#pragma unroll
      for (int r = 0; r < 4; r++) {
        float p = __expf(s_acc[nt][r] - m_r[r]);
        psum[r] += p;
        ph[(m0 + quad * 4 + r) * 72 + nt * 16 + l15] = f2bf(p);
      }
    }
#pragma unroll
    for (int r = 0; r < 4; r++) {
      float v = psum[r];
      v += __shfl_xor(v, 1);
      v += __shfl_xor(v, 2);
      v += __shfl_xor(v, 4);
      v += __shfl_xor(v, 8);
      l_r[r] = l_r[r] * alpha[r] + v;
    }
#pragma unroll
    for (int j = 0; j < 32; j++) {
#pragma unroll
      for (int r = 0; r < 4; r++) o_acc[j][r] *= alpha[r];
    }

    // ---- PV: 2 units of 256 d-rows; V0 in buf0 (drained at ds=3's sync) ----
#pragma unroll
    for (int vh = 0; vh < 2; vh++) {
      const int p = vh;  // V0 -> buf0, V1 -> buf1
      if (vh == 0) issueV(t0, 1, 1);
      else {
        const int tcn = (tc + 1 < TCH) ? tc + 1 : 0;  // wrap: dead prefetch, drained below
        issueK(t00 + tcn * BN, 0, 0);
      }
      __builtin_amdgcn_s_setprio(1);
#pragma unroll
      for (int ks = 0; ks < 2; ks++) {
        const int kk = ks * 32 + quad * 8;
        const int go = ((ks * 4 + quad) ^ x7) << 3;
        short8 ap = *(const short8*)&ph[(m0 + l15) * 72 + kk];
#pragma unroll
        for (int ntl = 0; ntl < 16; ntl++) {
          const int off = (ntl * 16 + l15) * 64 + go;
          short8 bv = *(const short8*)&sbuf[p][off];
          o_acc[vh * 16 + ntl] = MFMA16(ap, bv, o_acc[vh * 16 + ntl]);
        }
      }
      __builtin_amdgcn_s_setprio(0);
      __syncthreads();  // drains this unit's prefetch DMA
    }
  }

  // ---- epilogue: unnormalized partial O (bf16) + m/l stats ----
  const size_t obase = (((size_t)tp * Bb + b) * Ss + s0) * Dd;
#pragma unroll
  for (int j = 0; j < 32; j++) {
    const int col = (j >> 3) * 128 + (j & 7) * 16 + l15;
#pragma unroll
    for (int r = 0; r < 4; r++) {
      const int row = m0 + quad * 4 + r;
      opart[obase + (size_t)row * Dd + col] = f2bf(o_acc[j][r]);
    }
  }
  if (l15 == 0) {
    const size_t sbase = ((size_t)tp * Bb + b) * Ss + s0;
#pragma unroll
    for (int r = 0; r < 4; r++) {
      const int row = m0 + quad * 4 + r;
      mpart[sbase + row] = m_r[r];
      lpart[sbase + row] = l_r[r];
    }
  }
}

// Merge TP partitions: ctx = sum_p e^{m_p-M} O_p / sum_p e^{m_p-M} l_p
__global__ void combine_kernel(const u16* __restrict__ opart,
                               const float* __restrict__ mpart,
                               const float* __restrict__ lpart,
                               u16* __restrict__ ctx) {
  const int idx = blockIdx.x * blockDim.x + threadIdx.x;  // vec8 index
  const int vpr = Dd / 8;
  const int row = idx / vpr;         // b*Ss + s
  const int dv = (idx % vpr) * 8;
  float mv[TP], mM = -INFINITY;
#pragma unroll
  for (int p = 0; p < TP; p++) {
    mv[p] = mpart[(size_t)p * Bb * Ss + row];
    mM = fmaxf(mM, mv[p]);
  }
  float w[TP], denom = 0.f;
#pragma unroll
  for (int p = 0; p < TP; p++) {
    float e = __expf(mv[p] - mM);
    w[p] = e;
    denom += e * lpart[(size_t)p * Bb * Ss + row];
  }
  const float inv = 1.0f / denom;
  float acc[8];
#pragma unroll
  for (int e = 0; e < 8; e++) acc[e] = 0.f;
#pragma unroll
  for (int p = 0; p < TP; p++) {
    uint4 raw = *(const uint4*)&opart[(size_t)p * Bb * Ss * Dd + (size_t)row * Dd + dv];
    const u16* u = (const u16*)&raw;
#pragma unroll
    for (int e = 0; e < 8; e++) acc[e] += w[p] * bf2f(u[e]);
  }
  u16 outv[8];
#pragma unroll
  for (int e = 0; e < 8; e++) outv[e] = f2bf(acc[e] * inv);
  *(uint4*)&ctx[(size_t)row * Dd + dv] = *(const uint4*)outv;
}

// out[8192,512] = ctx_bf16 @ d4 + d5 ; 128x128 tile, 256 thr, wave = 64x64
__global__ __launch_bounds__(256, 2)
void proj_kernel(const u16* __restrict__ ctx,
                 const u16* __restrict__ d4t,  // [n][k]
                 const float* __restrict__ d5,
                 float* __restrict__ out) {
  __shared__ u16 a_lds[128 * 40], b_lds[128 * 40];
  const int tid = threadIdx.x;
  const int wave = tid >> 6, lane = tid & 63, quad = lane >> 4, l15 = lane & 15;
  const int m0w = (wave & 1) * 64, n0w = (wave >> 1) * 64;
  const int bm = blockIdx.x, bn = blockIdx.y;
  f32x4 acc[4][4];
#pragma unroll
  for (int i = 0; i < 4; i++)
#pragma unroll
    for (int j = 0; j < 4; j++) acc[i][j] = (f32x4){0.f, 0.f, 0.f, 0.f};

  const int srow = tid >> 2, scol = (tid & 3) * 8;
  for (int kt = 0; kt < 16; kt++) {
    const int k0 = kt * 32;
    __syncthreads();
#pragma unroll
    for (int pass = 0; pass < 2; pass++) {
      const int row = srow + pass * 64;
      *(uint4*)&a_lds[row * 40 + scol] =
          *(const uint4*)&ctx[(size_t)(bm * 128 + row) * Dd + k0 + scol];
      *(uint4*)&b_lds[row * 40 + scol] =
          *(const uint4*)&d4t[(size_t)(bn * 128 + row) * Dd + k0 + scol];
    }
    __syncthreads();
    short8 af[4], bfr[4];
#pragma unroll
    for (int i = 0; i < 4; i++)
      af[i] = *(const short8*)&a_lds[(m0w + 16 * i + l15) * 40 + quad * 8];
#pragma unroll
    for (int j = 0; j < 4; j++)
      bfr[j] = *(const short8*)&b_lds[(n0w + 16 * j + l15) * 40 + quad * 8];
#pragma unroll
    for (int i = 0; i < 4; i++)
#pragma unroll
      for (int j = 0; j < 4; j++) acc[i][j] = MFMA16(af[i], bfr[j], acc[i][j]);
  }
#pragma unroll
  for (int j = 0; j < 4; j++) {
    const int colg = bn * 128 + n0w + 16 * j + l15;
    const float bias = d5[colg];
#pragma unroll
    for (int i = 0; i < 4; i++) {
#pragma unroll
      for (int r = 0; r < 4; r++) {
        const int rowg = bm * 128 + m0w + 16 * i + quad * 4 + r;
        out[(size_t)rowg * 512 + colg] = acc[i][j][r] + bias;
      }
    }
  }
}

extern "C" void kernel_launch(void* const* d_in, const int* in_sizes, int n_in,
                              void* d_out, int out_size, void* d_ws, size_t ws_size,
                              hipStream_t stream) {
  (void)in_sizes; (void)n_in; (void)out_size; (void)ws_size;
  const float* d1 = (const float*)d_in[0];
  const float* d2 = (const float*)d_in[1];
  const float* d3 = (const float*)d_in[2];
  const float* d4 = (const float*)d_in[3];
  const float* d5 = (const float*)d_in[4];
  float* out = (float*)d_out;
  char* ws = (char*)d_ws;

  u16* qh_g = (u16*)(ws + O_QH);
  u16* ql_g = (u16*)(ws + O_QL);
  u16* d2th = (u16*)(ws + O_D2TH);
  u16* d2tl = (u16*)(ws + O_D2TL);
  u16* d3t  = (u16*)(ws + O_D3T);
  u16* d4t  = (u16*)(ws + O_D4T);
  u16* ctx  = (u16*)(ws + O_CTX);
  u16* opart = (u16*)(ws + O_OP);
  float* mpart = (float*)(ws + O_MP);
  float* lpart = (float*)(ws + O_LP);

  // d1 [b][s][d] -> bf16 hi/lo (elementwise)
  cvt_split_kernel<<<(Bb * Ss * Dd / 4) / 256, 256, 0, stream>>>(d1, qh_g, ql_g);
  // d2 [b][512][4096] -> [b][t][d] hi+lo
  transpose_split_kernel<<<dim3(128, 16, 2), dim3(32, 8), 0, stream>>>(d2, d2th, d2tl, 512, 4096);
  // d3 [b][4096][512] -> [b][d][t] hi only
  transpose_split_kernel<<<dim3(16, 128, 2), dim3(32, 8), 0, stream>>>(d3, d3t, nullptr, 4096, 512);
  // d4 [512][512] -> [n][k] hi only
  transpose_split_kernel<<<dim3(16, 16, 1), dim3(32, 8), 0, stream>>>(d4, d4t, nullptr, 512, 512);

  // 1D grid, XCD-clustered decode inside the kernel
  flash_part_kernel<<<dim3((Ss / BM) * TP * Bb), 256, 0, stream>>>(qh_g, ql_g, d2th, d2tl, d3t,
                                                                   opart, mpart, lpart);
  combine_kernel<<<(Bb * Ss * Dd / 8) / 256, 256, 0, stream>>>(opart, mpart, lpart, ctx);
  proj_kernel<<<dim3(64, 4), 256, 0, stream>>>(ctx, d4t, d5, out);
}

// Round 5
// 560.894 us; speedup vs baseline: 1.2581x; 1.1054x over previous
//
#include <hip/hip_runtime.h>

typedef unsigned short u16;
typedef __attribute__((ext_vector_type(8))) short short8;
typedef __attribute__((ext_vector_type(4))) float f32x4;

#define MFMA16(a, b, c) __builtin_amdgcn_mfma_f32_16x16x32_bf16((a), (b), (c), 0, 0, 0)

constexpr int Bb = 2, Ss = 4096, Tt = 4096, Dd = 512;
constexpr int BM = 64, BN = 64, TP = 4;
constexpr int TPART = Tt / TP;   // 1024
constexpr int TCH = TPART / BN;  // 16 T-chunks per partition

// ---- workspace layout (bytes) ----
constexpr size_t SZ_BF = (size_t)Bb * Ss * Dd * 2;  // 8,388,608 B: one bf16 [2][4096][512]
constexpr size_t O_QH  = 0;
constexpr size_t O_QL  = O_QH + SZ_BF;
constexpr size_t O_D2TH = O_QL + SZ_BF;
constexpr size_t O_D2TL = O_D2TH + SZ_BF;
constexpr size_t O_D3T  = O_D2TL + SZ_BF;
constexpr size_t O_D4T  = O_D3T + SZ_BF;
constexpr size_t O_CTX  = O_D4T + (size_t)512 * 512 * 2;
constexpr size_t O_OP   = O_CTX + SZ_BF;
constexpr size_t O_MP   = O_OP + (size_t)TP * SZ_BF;
constexpr size_t O_LP   = O_MP + (size_t)TP * Bb * Ss * 4;

__device__ __forceinline__ u16 f2bf(float x) {
  union { float f; unsigned u; } v; v.f = x;
  unsigned r = v.u + 0x7fffu + ((v.u >> 16) & 1u);  // RNE
  return (u16)(r >> 16);
}
__device__ __forceinline__ float bf2f(u16 h) {
  union { unsigned u; float f; } v; v.u = ((unsigned)h) << 16;
  return v.f;
}

// elementwise f32 -> bf16 hi + bf16 lo-residual (no transpose; d1 is already [b][s][d])
__global__ void cvt_split_kernel(const float* __restrict__ in,
                                 u16* __restrict__ outh, u16* __restrict__ outl) {
  const int i = blockIdx.x * 256 + threadIdx.x;
  float4 v = ((const float4*)in)[i];
  ushort4 hh, ll;
  hh.x = f2bf(v.x); ll.x = f2bf(v.x - bf2f(hh.x));
  hh.y = f2bf(v.y); ll.y = f2bf(v.y - bf2f(hh.y));
  hh.z = f2bf(v.z); ll.z = f2bf(v.z - bf2f(hh.z));
  hh.w = f2bf(v.w); ll.w = f2bf(v.w - bf2f(hh.w));
  ((ushort4*)outh)[i] = hh;
  ((ushort4*)outl)[i] = ll;
}

// in: [batch][R][C] f32  ->  outh/outl: [batch][C][R] bf16 (hi, optional lo residual)
__global__ void transpose_split_kernel(const float* __restrict__ in,
                                       u16* __restrict__ outh,
                                       u16* __restrict__ outl,
                                       int R, int C) {
  __shared__ float tile[32][33];
  int b = blockIdx.z;
  const float* inb = in + (size_t)b * R * C;
  int x = blockIdx.x * 32 + threadIdx.x;
  int y0 = blockIdx.y * 32;
  for (int j = threadIdx.y; j < 32; j += 8)
    tile[j][threadIdx.x] = inb[(size_t)(y0 + j) * C + x];
  __syncthreads();
  size_t ob = (size_t)b * C * R;
  for (int j = threadIdx.y; j < 32; j += 8) {
    float v = tile[threadIdx.x][j];
    size_t oi = ob + (size_t)(blockIdx.x * 32 + j) * R + (y0 + threadIdx.x);
    u16 h = f2bf(v);
    outh[oi] = h;
    if (outl) outl[oi] = f2bf(v - bf2f(h));
  }
}

// Flash attention partial over one T-partition.
// grid (Ss/BM=64, TP, Bb), block 256 (4 waves; wave w owns Q-rows w*16..w*16+15)
// v6 = the proven 405us v1 structure (reg staging, 3D grid, no DMA, no persistent
// staging regs) with ONLY:
//  - granule swizzle s=((g+2r)&7)|(g&8) on K/V/ph LDS stores AND reads.
//    At pitch 136/72, bank(r,g) = 4*(r+g) mod 32 -> 8 lanes/bank on every
//    ds_read_b128 (8-way). Swizzled: 4*(3r+g) mod 32, 3 coprime 8 -> 2-way (free).
//    Pitch changes can't fix this (16B-aligned rows force pitch_dw%4==0).
//  - Q fragment loads hoisted above the stage barrier (latency hides under it)
//  - ap (nc-invariant) hoisted once per tc
//  - s_setprio(1) around MFMA clusters
__global__ __launch_bounds__(256, 2)
void flash_part_kernel(const u16* __restrict__ qh_g,
                       const u16* __restrict__ ql_g,
                       const u16* __restrict__ d2th,
                       const u16* __restrict__ d2tl,
                       const u16* __restrict__ d3t,
                       u16* __restrict__ opart,
                       float* __restrict__ mpart,
                       float* __restrict__ lpart) {
  // K tile: 64 t-rows x 128 d-cols, pitch 136 (16B-aligned rows)
  // V tile: 128 d-rows x 64 t-cols, pitch 72
  // P tile: 64 s-rows x 64 t-cols, pitch 72 (per-wave private rows)
  __shared__ u16 kh[64 * 136], kl[64 * 136];
  __shared__ u16 vb[128 * 72];
  __shared__ u16 ph[64 * 72];

  const int tid = threadIdx.x;
  const int wave = tid >> 6, lane = tid & 63, quad = lane >> 4, l15 = lane & 15;
  const int m0 = wave * 16;
  const int s0 = blockIdx.x * BM, tp = blockIdx.y, b = blockIdx.z;

  f32x4 o_acc[32];
#pragma unroll
  for (int i = 0; i < 32; i++) o_acc[i] = (f32x4){0.f, 0.f, 0.f, 0.f};
  float m_r[4] = {-INFINITY, -INFINITY, -INFINITY, -INFINITY};
  float l_r[4] = {0.f, 0.f, 0.f, 0.f};

  const u16* qh_row = qh_g + ((size_t)b * Ss + s0 + m0 + l15) * Dd + quad * 8;
  const u16* ql_row = ql_g + ((size_t)b * Ss + s0 + m0 + l15) * Dd + quad * 8;
  const u16* kh_b = d2th + (size_t)b * Tt * Dd;
  const u16* kl_b = d2tl + (size_t)b * Tt * Dd;
  const u16* v_b  = d3t  + (size_t)b * Dd * Tt;

  const int krow = tid >> 2, kcol = (tid & 3) * 32;  // K stage: 64 x 128
  const int vrow = tid >> 1, vcol = (tid & 1) * 32;  // V stage: 128 x 64

  for (int tc = 0; tc < TCH; tc++) {
    const int t0 = tp * TPART + tc * BN;
    f32x4 s_acc[4];
#pragma unroll
    for (int nt = 0; nt < 4; nt++) s_acc[nt] = (f32x4){0.f, 0.f, 0.f, 0.f};

    // ---- QK^T over D in chunks of 128 ----
    for (int ds = 0; ds < 4; ds++) {
      const int d0 = ds * 128;
      __syncthreads();
      {  // stage K chunk hi+lo with granule swizzle on the LDS store side
        const u16* sh = kh_b + (size_t)(t0 + krow) * Dd + d0 + kcol;
        const u16* sl = kl_b + (size_t)(t0 + krow) * Dd + d0 + kcol;
        const int gb = kcol >> 3;  // base granule (16B units)
#pragma unroll
        for (int j = 0; j < 4; j++) {
          const int g = gb + j;
          const int s = ((g + 2 * krow) & 7) | (g & 8);
          *(uint4*)&kh[krow * 136 + s * 8] = *(const uint4*)(sh + j * 8);
          *(uint4*)&kl[krow * 136 + s * 8] = *(const uint4*)(sl + j * 8);
        }
      }
      // Q fragments (global, L2-warm; no LDS dep -> issue before the barrier so
      // their latency hides under the barrier wait)
      short8 ah[4], al[4];
#pragma unroll
      for (int ks = 0; ks < 4; ks++) {
        ah[ks] = *(const short8*)(qh_row + d0 + ks * 32);
        al[ks] = *(const short8*)(ql_row + d0 + ks * 32);
      }
      __syncthreads();
      __builtin_amdgcn_s_setprio(1);
#pragma unroll
      for (int ks = 0; ks < 4; ks++) {
        const int g0 = ks * 4 + quad;
        const int sg = ((g0 + 2 * l15) & 7) | (g0 & 8);  // (2*(nt*16))%8==0
#pragma unroll
        for (int nt = 0; nt < 4; nt++) {
          const int off = (nt * 16 + l15) * 136 + sg * 8;
          short8 bh = *(const short8*)&kh[off];
          short8 bl = *(const short8*)&kl[off];
          s_acc[nt] = MFMA16(ah[ks], bh, s_acc[nt]);
          s_acc[nt] = MFMA16(al[ks], bh, s_acc[nt]);
          s_acc[nt] = MFMA16(ah[ks], bl, s_acc[nt]);
        }
      }
      __builtin_amdgcn_s_setprio(0);
    }

    // ---- online softmax (C layout: row=quad*4+r, col=nt*16+l15; rows intra-wave) ----
    float alpha[4], psum[4];
#pragma unroll
    for (int r = 0; r < 4; r++) {
      float v = fmaxf(fmaxf(s_acc[0][r], s_acc[1][r]), fmaxf(s_acc[2][r], s_acc[3][r]));
      v = fmaxf(v, __shfl_xor(v, 1));
      v = fmaxf(v, __shfl_xor(v, 2));
      v = fmaxf(v, __shfl_xor(v, 4));
      v = fmaxf(v, __shfl_xor(v, 8));
      float mn = fmaxf(m_r[r], v);
      alpha[r] = __expf(m_r[r] - mn);
      m_r[r] = mn;
      psum[r] = 0.f;
    }
#pragma unroll
    for (int nt = 0; nt < 4; nt++) {
#pragma unroll
      for (int r = 0; r < 4; r++) {
        float p = __expf(s_acc[nt][r] - m_r[r]);
        psum[r] += p;
        // swizzled ph store: row'=m0+quad*4+r, col=nt*16+l15 -> granule 2nt+(l15>>3)
        const int sp = (2 * nt + (l15 >> 3) + 2 * r) & 7;  // (2*row')%8 == 2r
        ph[(m0 + quad * 4 + r) * 72 + sp * 8 + (l15 & 7)] = f2bf(p);
      }
    }
#pragma unroll
    for (int r = 0; r < 4; r++) {
      float v = psum[r];
      v += __shfl_xor(v, 1);
      v += __shfl_xor(v, 2);
      v += __shfl_xor(v, 4);
      v += __shfl_xor(v, 8);
      l_r[r] = l_r[r] * alpha[r] + v;
    }
#pragma unroll
    for (int j = 0; j < 32; j++) {
#pragma unroll
      for (int r = 0; r < 4; r++) o_acc[j][r] *= alpha[r];
    }

    // ap is nc-invariant: hoist once per tc (own-wave rows, written above)
    short8 ap[2];
#pragma unroll
    for (int ks = 0; ks < 2; ks++) {
      const int g0 = ks * 4 + quad;
      const int sg = (g0 + 2 * l15) & 7;
      ap[ks] = *(const short8*)&ph[(m0 + l15) * 72 + sg * 8];
    }

    // ---- PV: O += P @ V, output d-cols in chunks of 128 ----
#pragma unroll
    for (int nc = 0; nc < 4; nc++) {
      __syncthreads();
      {  // stage V chunk [128 d][64 t] with granule swizzle (d3t is [b][d][t])
        const u16* sv = v_b + (size_t)(nc * 128 + vrow) * Tt + t0 + vcol;
        const int gb = vcol >> 3;
#pragma unroll
        for (int j = 0; j < 4; j++) {
          const int g = gb + j;
          const int s = (g + 2 * vrow) & 7;
          *(uint4*)&vb[vrow * 72 + s * 8] = *(const uint4*)(sv + j * 8);
        }
      }
      __syncthreads();
      __builtin_amdgcn_s_setprio(1);
#pragma unroll
      for (int ks = 0; ks < 2; ks++) {
        const int g0 = ks * 4 + quad;
        const int sg = (g0 + 2 * l15) & 7;
#pragma unroll
        for (int nt = 0; nt < 8; nt++) {
          short8 bv = *(const short8*)&vb[(nt * 16 + l15) * 72 + sg * 8];
          o_acc[nc * 8 + nt] = MFMA16(ap[ks], bv, o_acc[nc * 8 + nt]);
        }
      }
      __builtin_amdgcn_s_setprio(0);
    }
  }

  // ---- epilogue: unnormalized partial O (bf16) + m/l stats ----
  const size_t obase = (((size_t)tp * Bb + b) * Ss + s0) * Dd;
#pragma unroll
  for (int j = 0; j < 32; j++) {
    const int col = (j >> 3) * 128 + (j & 7) * 16 + l15;
#pragma unroll
    for (int r = 0; r < 4; r++) {
      const int row = m0 + quad * 4 + r;
      opart[obase + (size_t)row * Dd + col] = f2bf(o_acc[j][r]);
    }
  }
  if (l15 == 0) {
    const size_t sbase = ((size_t)tp * Bb + b) * Ss + s0;
#pragma unroll
    for (int r = 0; r < 4; r++) {
      const int row = m0 + quad * 4 + r;
      mpart[sbase + row] = m_r[r];
      lpart[sbase + row] = l_r[r];
    }
  }
}

// Merge TP partitions: ctx = sum_p e^{m_p-M} O_p / sum_p e^{m_p-M} l_p
__global__ void combine_kernel(const u16* __restrict__ opart,
                               const float* __restrict__ mpart,
                               const float* __restrict__ lpart,
                               u16* __restrict__ ctx) {
  const int idx = blockIdx.x * blockDim.x + threadIdx.x;  // vec8 index
  const int vpr = Dd / 8;
  const int row = idx / vpr;         // b*Ss + s
  const int dv = (idx % vpr) * 8;
  float mv[TP], mM = -INFINITY;
#pragma unroll
  for (int p = 0; p < TP; p++) {
    mv[p] = mpart[(size_t)p * Bb * Ss + row];
    mM = fmaxf(mM, mv[p]);
  }
  float w[TP], denom = 0.f;
#pragma unroll
  for (int p = 0; p < TP; p++) {
    float e = __expf(mv[p] - mM);
    w[p] = e;
    denom += e * lpart[(size_t)p * Bb * Ss + row];
  }
  const float inv = 1.0f / denom;
  float acc[8];
#pragma unroll
  for (int e = 0; e < 8; e++) acc[e] = 0.f;
#pragma unroll
  for (int p = 0; p < TP; p++) {
    uint4 raw = *(const uint4*)&opart[(size_t)p * Bb * Ss * Dd + (size_t)row * Dd + dv];
    const u16* u = (const u16*)&raw;
#pragma unroll
    for (int e = 0; e < 8; e++) acc[e] += w[p] * bf2f(u[e]);
  }
  u16 outv[8];
#pragma unroll
  for (int e = 0; e < 8; e++) outv[e] = f2bf(acc[e] * inv);
  *(uint4*)&ctx[(size_t)row * Dd + dv] = *(const uint4*)outv;
}

// out[8192,512] = ctx_bf16 @ d4 + d5 ; 128x128 tile, 256 thr, wave = 64x64
__global__ __launch_bounds__(256, 2)
void proj_kernel(const u16* __restrict__ ctx,
                 const u16* __restrict__ d4t,  // [n][k]
                 const float* __restrict__ d5,
                 float* __restrict__ out) {
  __shared__ u16 a_lds[128 * 40], b_lds[128 * 40];
  const int tid = threadIdx.x;
  const int wave = tid >> 6, lane = tid & 63, quad = lane >> 4, l15 = lane & 15;
  const int m0w = (wave & 1) * 64, n0w = (wave >> 1) * 64;
  const int bm = blockIdx.x, bn = blockIdx.y;
  f32x4 acc[4][4];
#pragma unroll
  for (int i = 0; i < 4; i++)
#pragma unroll
    for (int j = 0; j < 4; j++) acc[i][j] = (f32x4){0.f, 0.f, 0.f, 0.f};

  const int srow = tid >> 2, scol = (tid & 3) * 8;
  for (int kt = 0; kt < 16; kt++) {
    const int k0 = kt * 32;
    __syncthreads();
#pragma unroll
    for (int pass = 0; pass < 2; pass++) {
      const int row = srow + pass * 64;
      *(uint4*)&a_lds[row * 40 + scol] =
          *(const uint4*)&ctx[(size_t)(bm * 128 + row) * Dd + k0 + scol];
      *(uint4*)&b_lds[row * 40 + scol] =
          *(const uint4*)&d4t[(size_t)(bn * 128 + row) * Dd + k0 + scol];
    }
    __syncthreads();
    short8 af[4], bfr[4];
#pragma unroll
    for (int i = 0; i < 4; i++)
      af[i] = *(const short8*)&a_lds[(m0w + 16 * i + l15) * 40 + quad * 8];
#pragma unroll
    for (int j = 0; j < 4; j++)
      bfr[j] = *(const short8*)&b_lds[(n0w + 16 * j + l15) * 40 + quad * 8];
#pragma unroll
    for (int i = 0; i < 4; i++)
#pragma unroll
      for (int j = 0; j < 4; j++) acc[i][j] = MFMA16(af[i], bfr[j], acc[i][j]);
  }
#pragma unroll
  for (int j = 0; j < 4; j++) {
    const int colg = bn * 128 + n0w + 16 * j + l15;
    const float bias = d5[colg];
#pragma unroll
    for (int i = 0; i < 4; i++) {
#pragma unroll
      for (int r = 0; r < 4; r++) {
        const int rowg = bm * 128 + m0w + 16 * i + quad * 4 + r;
        out[(size_t)rowg * 512 + colg] = acc[i][j][r] + bias;
      }
    }
  }
}

extern "C" void kernel_launch(void* const* d_in, const int* in_sizes, int n_in,
                              void* d_out, int out_size, void* d_ws, size_t ws_size,
                              hipStream_t stream) {
  (void)in_sizes; (void)n_in; (void)out_size; (void)ws_size;
  const float* d1 = (const float*)d_in[0];
  const float* d2 = (const float*)d_in[1];
  const float* d3 = (const float*)d_in[2];
  const float* d4 = (const float*)d_in[3];
  const float* d5 = (const float*)d_in[4];
  float* out = (float*)d_out;
  char* ws = (char*)d_ws;

  u16* qh_g = (u16*)(ws + O_QH);
  u16* ql_g = (u16*)(ws + O_QL);
  u16* d2th = (u16*)(ws + O_D2TH);
  u16* d2tl = (u16*)(ws + O_D2TL);
  u16* d3t  = (u16*)(ws + O_D3T);
  u16* d4t  = (u16*)(ws + O_D4T);
  u16* ctx  = (u16*)(ws + O_CTX);
  u16* opart = (u16*)(ws + O_OP);
  float* mpart = (float*)(ws + O_MP);
  float* lpart = (float*)(ws + O_LP);

  // d1 [b][s][d] -> bf16 hi/lo (elementwise)
  cvt_split_kernel<<<(Bb * Ss * Dd / 4) / 256, 256, 0, stream>>>(d1, qh_g, ql_g);
  // d2 [b][512][4096] -> [b][t][d] hi+lo
  transpose_split_kernel<<<dim3(128, 16, 2), dim3(32, 8), 0, stream>>>(d2, d2th, d2tl, 512, 4096);
  // d3 [b][4096][512] -> [b][d][t] hi only
  transpose_split_kernel<<<dim3(16, 128, 2), dim3(32, 8), 0, stream>>>(d3, d3t, nullptr, 4096, 512);
  // d4 [512][512] -> [n][k] hi only
  transpose_split_kernel<<<dim3(16, 16, 1), dim3(32, 8), 0, stream>>>(d4, d4t, nullptr, 512, 512);

  flash_part_kernel<<<dim3(Ss / BM, TP, Bb), 256, 0, stream>>>(qh_g, ql_g, d2th, d2tl, d3t,
                                                               opart, mpart, lpart);
  combine_kernel<<<(Bb * Ss * Dd / 8) / 256, 256, 0, stream>>>(opart, mpart, lpart, ctx);
  proj_kernel<<<dim3(64, 4), 256, 0, stream>>>(ctx, d4t, d5, out);
}